// Round 15
// baseline (221.041 us; speedup 1.0000x reference)
//
#include <hip/hip_runtime.h>
#include <cstdint>

#define N_NODES 50000
#define N_EDGES 800000
#define N_PAIRS 200000
#define IN_DIM 128
#define HID 64
#define N_WAVES_GEMM (N_NODES / 16)           // 3125
#define NB1 196                               // high-byte bins AND edge chunks
#define CHUNK ((N_EDGES + NB1 - 1) / NB1)     // 4082
#define MHIST (NB1 * NB1)                     // 38416
#define SBG ((MHIST + 255) / 256)             // 151 scan blocks
#define MB_GEMM ((N_WAVES_GEMM + 3) / 4)      // 782
#define NODE_BLOCKS ((N_NODES + 3) / 4)       // 12500
#define MEMBER_BLOCKS (N_PAIRS / 32)          // 6250 (32 pairs/block)

typedef __attribute__((ext_vector_type(8))) short bf16x8;
typedef __attribute__((ext_vector_type(4))) float f32x4;

__device__ __forceinline__ unsigned short bf16_rne(float f) {
    unsigned u = __float_as_uint(f);
    unsigned t = u + 0x7FFFu + ((u >> 16) & 1u);
    return (unsigned short)(t >> 16);
}
__device__ __forceinline__ void bf2f(unsigned u, float& a, float& b) {
    a = __uint_as_float(u << 16);
    b = __uint_as_float(u & 0xFFFF0000u);
}

// ---- fused: MSD pass-1 histogram (blocks 0..195) + W fragment prep ----
__global__ __launch_bounds__(256) void hist_prep(
    const int* __restrict__ dst, int* __restrict__ histHi,
    const float* __restrict__ W1, const float* __restrict__ W2,
    unsigned short* __restrict__ w1hi, unsigned short* __restrict__ w1lo,
    unsigned short* __restrict__ w2hi, unsigned short* __restrict__ w2lo)
{
    const int t = threadIdx.x, b = blockIdx.x;
    if (b < NB1) {
        __shared__ int hist[256];
        hist[t] = 0; __syncthreads();
        const int beg = b * CHUNK, end = min(beg + CHUNK, N_EDGES);
        for (int e = beg + t; e < end; e += 256) atomicAdd(&hist[dst[e] >> 8], 1);
        __syncthreads();
        if (t < NB1) histHi[t * NB1 + b] = hist[t];
    } else {
        int tid = (b - NB1) * 256 + t;
        if (tid < 8192) {
            int jj = tid & 7, lane = (tid >> 3) & 63, tt = (tid >> 9) & 3, ks = tid >> 11;
            int k = ks * 32 + (lane >> 4) * 8 + jj;
            int n = tt * 16 + (lane & 15);
            float f = W1[k * HID + n];
            unsigned short hi = bf16_rne(f);
            float fhi = __uint_as_float(((unsigned)hi) << 16);
            w1hi[tid] = hi;
            w1lo[tid] = bf16_rne(f - fhi);
        }
        if (tid < 4096) {
            int jj = tid & 7, lane = (tid >> 3) & 63, tt = (tid >> 9) & 3, ks = tid >> 11;
            int k = ks * 32 + (lane >> 4) * 8 + jj;
            int n = tt * 16 + (lane & 15);
            float f = W2[k * HID + n];
            unsigned short hi = bf16_rne(f);
            float fhi = __uint_as_float(((unsigned)hi) << 16);
            w2hi[tid] = hi;
            w2lo[tid] = bf16_rne(f - fhi);
        }
    }
}

// device-wide scan step 1 (standalone, tiny)
__global__ __launch_bounds__(256) void scan1g(
    int* __restrict__ histHi, int* __restrict__ bsums)
{
    __shared__ int sh[256];
    const int t = threadIdx.x;
    const int i = blockIdx.x * 256 + t;
    int v = (i < MHIST) ? histHi[i] : 0;
    sh[t] = v; __syncthreads();
    #pragma unroll
    for (int off = 1; off < 256; off <<= 1) {
        int x = sh[t];
        int a = (t >= off) ? sh[t - off] : 0;
        __syncthreads();
        sh[t] = x + a;
        __syncthreads();
    }
    if (i < MHIST) histHi[i] = sh[t] - v;
    if (t == 255) bsums[blockIdx.x] = sh[255];
}

// in-block exclusive scan of the 151 bsums partials -> exb[]
__device__ __forceinline__ void scan_bsums(const int* __restrict__ bsums,
                                           int* sh, int* exb, int t)
{
    int v = (t < SBG) ? bsums[t] : 0;
    sh[t] = v; __syncthreads();
    #pragma unroll
    for (int off = 1; off < 256; off <<= 1) {
        int x = sh[t];
        int a = (t >= off) ? sh[t - off] : 0;
        __syncthreads();
        sh[t] = x + a;
        __syncthreads();
    }
    exb[t] = sh[t] - v;
    __syncthreads();
}

// layer-1 GEMM body: fp32 x, split-bf16 (hi*hi + hi*lo + lo*hi); z stored bf16.
__device__ __forceinline__ void gemm1_body(
    int wave, int lane,
    const float* __restrict__ x,
    const unsigned short* __restrict__ whi, const unsigned short* __restrict__ wlo,
    const float* __restrict__ al, const float* __restrict__ ar,
    unsigned short* __restrict__ z, float* __restrict__ el, float* __restrict__ er)
{
    const int i0 = wave * 16;
    const int m = lane & 15, quad = lane >> 4;
    f32x4 acc[4] = {{0.f,0.f,0.f,0.f},{0.f,0.f,0.f,0.f},{0.f,0.f,0.f,0.f},{0.f,0.f,0.f,0.f}};
    const float* xrow = x + (size_t)(i0 + m) * IN_DIM;

    #pragma unroll 1
    for (int ks = 0; ks < 4; ++ks) {
        const float4 xv0 = *(const float4*)&xrow[ks * 32 + quad * 8];
        const float4 xv1 = *(const float4*)&xrow[ks * 32 + quad * 8 + 4];
        float xs[8] = {xv0.x, xv0.y, xv0.z, xv0.w, xv1.x, xv1.y, xv1.z, xv1.w};
        bf16x8 ahi, alo;
        #pragma unroll
        for (int jj = 0; jj < 8; ++jj) {
            unsigned short hb = bf16_rne(xs[jj]);
            float fhi = __uint_as_float(((unsigned)hb) << 16);
            ahi[jj] = (short)hb;
            alo[jj] = (short)bf16_rne(xs[jj] - fhi);
        }
        #pragma unroll
        for (int t = 0; t < 4; ++t) {
            const bf16x8 bhi = *(const bf16x8*)&whi[(((ks * 4 + t) * 64) + lane) * 8];
            const bf16x8 blo = *(const bf16x8*)&wlo[(((ks * 4 + t) * 64) + lane) * 8];
            acc[t] = __builtin_amdgcn_mfma_f32_16x16x32_bf16(ahi, bhi, acc[t], 0, 0, 0);
            acc[t] = __builtin_amdgcn_mfma_f32_16x16x32_bf16(ahi, blo, acc[t], 0, 0, 0);
            acc[t] = __builtin_amdgcn_mfma_f32_16x16x32_bf16(alo, bhi, acc[t], 0, 0, 0);
        }
    }
    #pragma unroll
    for (int r = 0; r < 4; ++r) {
        const int row = quad * 4 + r;
        float se = 0.f, sr = 0.f;
        #pragma unroll
        for (int t = 0; t < 4; ++t) {
            float v = acc[t][r];
            z[(size_t)(i0 + row) * HID + t * 16 + m] = bf16_rne(v);
            se = fmaf(v, al[t * 16 + m], se);
            sr = fmaf(v, ar[t * 16 + m], sr);
        }
        #pragma unroll
        for (int off = 1; off < 16; off <<= 1) {
            se += __shfl_xor(se, off, 64);
            sr += __shfl_xor(sr, off, 64);
        }
        if (m == 0) { el[i0 + row] = se; er[i0 + row] = sr; }
    }
}

// fused: MSD pass-1 scatter (blocks 0..195) + layer-1 GEMM (blocks 196..).
__global__ __launch_bounds__(256) void scatter_gemm1(
    const int* __restrict__ src, const int* __restrict__ dst,
    const int* __restrict__ histEx, const int* __restrict__ bsums,
    unsigned* __restrict__ pairs,
    const float* __restrict__ x,
    const unsigned short* __restrict__ whi, const unsigned short* __restrict__ wlo,
    const float* __restrict__ al, const float* __restrict__ ar,
    unsigned short* __restrict__ z, float* __restrict__ el, float* __restrict__ er)
{
    const int b = blockIdx.x;
    if (b < NB1) {
        __shared__ int sh[256], exb[256], base[256];
        const int t = threadIdx.y * 64 + threadIdx.x;
        scan_bsums(bsums, sh, exb, t);
        if (t < NB1) {
            int idx = t * NB1 + b;
            base[t] = histEx[idx] + exb[idx >> 8];
        }
        __syncthreads();
        const int beg = b * CHUNK, end = min(beg + CHUNK, N_EDGES);
        for (int e = beg + t; e < end; e += 256) {
            int s = src[e], d = dst[e];
            int pos = atomicAdd(&base[d >> 8], 1);
            pairs[pos] = ((unsigned)s << 16) | (unsigned)d;   // both ids < 2^16
        }
    } else {
        const int wave = (b - NB1) * 4 + threadIdx.y;
        if (wave < N_WAVES_GEMM)
            gemm1_body(wave, threadIdx.x, x, whi, wlo, al, ar, z, el, er);
    }
}

// ---- MSD pass 2: one block per 256-node segment -> row_start + csr_src (u16) ----
__global__ __launch_bounds__(256) void seg_sort(
    const unsigned* __restrict__ pairs, const int* __restrict__ histEx,
    const int* __restrict__ bsums,
    int* __restrict__ row_start, unsigned short* __restrict__ csr_src)
{
    __shared__ int sh[256], exb[256], hist[256], sc[256], offs[256];
    const int t = threadIdx.x, b = blockIdx.x;
    scan_bsums(bsums, sh, exb, t);
    const int i0 = b * NB1;
    const int segStart = histEx[i0] + exb[i0 >> 8];
    int segEnd = N_EDGES;
    if (b < NB1 - 1) {
        const int i1 = (b + 1) * NB1;
        segEnd = histEx[i1] + exb[i1 >> 8];
    }
    hist[t] = 0; __syncthreads();
    for (int i = segStart + t; i < segEnd; i += 256)
        atomicAdd(&hist[pairs[i] & 255], 1);
    __syncthreads();
    int v = hist[t]; sc[t] = v; __syncthreads();
    #pragma unroll
    for (int off = 1; off < 256; off <<= 1) {
        int x = sc[t];
        int a = (t >= off) ? sc[t - off] : 0;
        __syncthreads();
        sc[t] = x + a;
        __syncthreads();
    }
    const int excl = sc[t] - v;
    offs[t] = segStart + excl;
    const int node = b * 256 + t;
    if (node <= N_NODES) row_start[node] = segStart + excl;
    __syncthreads();
    for (int i = segStart + t; i < segEnd; i += 256) {
        unsigned p = pairs[i];
        int pos = atomicAdd(&offs[p & 255], 1);
        csr_src[pos] = (unsigned short)(p >> 16);
    }
}

// per-dst-node softmax-aggregate + relu body. One wave per node.
// 16 edge slots (es = lane>>2) x 4 feature lanes (fl = lane&3, 16 feats each):
// a full 16-edge batch is in flight in ONE round trip (typical deg<=16 node
// does csr -> el/z -> done). Next-batch prefetch only issued if needed
// (wave-uniform branch -> no dummy-load waits).
// LAST=false: writes bf16 h row. LAST=true: writes head dots a_s,a_d only.
template <bool LAST>
__device__ __forceinline__ void agg_body(
    int i, int lane,
    const int* __restrict__ row_start, const unsigned short* __restrict__ csr_src,
    const float* __restrict__ el, const float* __restrict__ er,
    const unsigned short* __restrict__ z, unsigned short* __restrict__ h,
    const float* __restrict__ Wc, float* __restrict__ as, float* __restrict__ ad)
{
    const int rb = row_start[i], re = row_start[i + 1];
    const float er_i = er[i];
    const int es = lane >> 2;
    const int fl = lane & 3;

    float acc[16];
    #pragma unroll
    for (int q = 0; q < 16; ++q) acc[q] = 0.f;
    float den = 0.f;

    int e = rb + es;
    bool v = e < re;
    int s = v ? (int)csr_src[e] : 0;
    float elv = el[s];
    const uint4* zr = (const uint4*)(z + (size_t)s * HID);
    uint4 z0 = zr[fl * 2], z1 = zr[fl * 2 + 1];

    for (int e0 = rb;;) {
        const int e0n = e0 + 16;
        const bool more = e0n < re;           // wave-uniform
        int sN = 0; bool vN = false; float elN = 0.f;
        uint4 zN0, zN1;
        if (more) {                            // prefetch next batch
            const int eN = e0n + es;
            vN = eN < re;
            sN = vN ? (int)csr_src[eN] : 0;
            elN = el[sN];
            const uint4* zrN = (const uint4*)(z + (size_t)sN * HID);
            zN0 = zrN[fl * 2]; zN1 = zrN[fl * 2 + 1];
        }
        // compute current batch
        float x = elv + er_i;
        float lr = x > 0.f ? x : 0.2f * x;
        float ex = v ? __expf(lr) : 0.f;
        float zf[16];
        bf2f(z0.x, zf[0], zf[1]);  bf2f(z0.y, zf[2], zf[3]);
        bf2f(z0.z, zf[4], zf[5]);  bf2f(z0.w, zf[6], zf[7]);
        bf2f(z1.x, zf[8], zf[9]);  bf2f(z1.y, zf[10], zf[11]);
        bf2f(z1.z, zf[12], zf[13]); bf2f(z1.w, zf[14], zf[15]);
        #pragma unroll
        for (int q = 0; q < 16; ++q) acc[q] = fmaf(ex, zf[q], acc[q]);
        den += ex;

        if (!more) break;
        s = sN; v = vN; elv = elN; z0 = zN0; z1 = zN1; e0 = e0n;
    }
    // reduce across the 16 edge slots (lane bits 2..5)
    #pragma unroll
    for (int off = 4; off < 64; off <<= 1) {
        #pragma unroll
        for (int q = 0; q < 16; ++q) acc[q] += __shfl_xor(acc[q], off, 64);
        den += __shfl_xor(den, off, 64);
    }
    if (es == 0) {                             // lanes 0..3
        float inv = 1.f / fmaxf(den, 1e-9f);
        float hv[16];
        #pragma unroll
        for (int q = 0; q < 16; ++q) hv[q] = fmaxf(acc[q] * inv, 0.f);
        if (LAST) {
            float ps = 0.f, pd = 0.f;
            #pragma unroll
            for (int q = 0; q < 16; ++q) {
                ps = fmaf(hv[q], Wc[fl * 16 + q], ps);
                pd = fmaf(hv[q], Wc[HID + fl * 16 + q], pd);
            }
            ps += __shfl_xor(ps, 1, 64); ps += __shfl_xor(ps, 2, 64);
            pd += __shfl_xor(pd, 1, 64); pd += __shfl_xor(pd, 2, 64);
            if (fl == 0) { as[i] = ps; ad[i] = pd; }
        } else {
            unsigned short o[16];
            #pragma unroll
            for (int q = 0; q < 16; ++q) o[q] = bf16_rne(hv[q]);
            uint4 p0, p1;
            p0.x = (unsigned)o[0]  | ((unsigned)o[1]  << 16);
            p0.y = (unsigned)o[2]  | ((unsigned)o[3]  << 16);
            p0.z = (unsigned)o[4]  | ((unsigned)o[5]  << 16);
            p0.w = (unsigned)o[6]  | ((unsigned)o[7]  << 16);
            p1.x = (unsigned)o[8]  | ((unsigned)o[9]  << 16);
            p1.y = (unsigned)o[10] | ((unsigned)o[11] << 16);
            p1.z = (unsigned)o[12] | ((unsigned)o[13] << 16);
            p1.w = (unsigned)o[14] | ((unsigned)o[15] << 16);
            uint4* hr = (uint4*)(h + (size_t)i * HID);
            hr[fl * 2] = p0; hr[fl * 2 + 1] = p1;
        }
    }
}

// layer-1 aggregate (standalone)
__global__ __launch_bounds__(256) void agg1(
    const int* __restrict__ row_start, const unsigned short* __restrict__ csr_src,
    const float* __restrict__ el, const float* __restrict__ er,
    const unsigned short* __restrict__ z, unsigned short* __restrict__ h)
{
    const int i = blockIdx.x * 4 + threadIdx.y;
    if (i < N_NODES)
        agg_body<false>(i, threadIdx.x, row_start, csr_src, el, er, z, h,
                        nullptr, nullptr, nullptr);
}

// fused: layer-2 GEMM (blocks 0..781) + pair membership (782..7031).
__global__ __launch_bounds__(256) void gemm2_member(
    const unsigned short* __restrict__ x,
    const unsigned short* __restrict__ whi, const unsigned short* __restrict__ wlo,
    const float* __restrict__ al, const float* __restrict__ ar,
    unsigned short* __restrict__ z, float* __restrict__ el, float* __restrict__ er,
    const int* __restrict__ row_start, const unsigned short* __restrict__ csr_src,
    const int* __restrict__ ps, const int* __restrict__ pd, int* __restrict__ found)
{
    const int lane = threadIdx.x, b = blockIdx.x;
    if (b < MB_GEMM) {
        const int wave = b * 4 + threadIdx.y;
        if (wave >= N_WAVES_GEMM) return;
        const int i0 = wave * 16;
        const int m = lane & 15, quad = lane >> 4;
        f32x4 acc[4] = {{0.f,0.f,0.f,0.f},{0.f,0.f,0.f,0.f},{0.f,0.f,0.f,0.f},{0.f,0.f,0.f,0.f}};
        const unsigned short* xrow = x + (size_t)(i0 + m) * HID;
        #pragma unroll 1
        for (int ks = 0; ks < 2; ++ks) {
            const bf16x8 a = *(const bf16x8*)&xrow[ks * 32 + quad * 8];
            #pragma unroll
            for (int t = 0; t < 4; ++t) {
                const bf16x8 bhi = *(const bf16x8*)&whi[(((ks * 4 + t) * 64) + lane) * 8];
                const bf16x8 blo = *(const bf16x8*)&wlo[(((ks * 4 + t) * 64) + lane) * 8];
                acc[t] = __builtin_amdgcn_mfma_f32_16x16x32_bf16(a, bhi, acc[t], 0, 0, 0);
                acc[t] = __builtin_amdgcn_mfma_f32_16x16x32_bf16(a, blo, acc[t], 0, 0, 0);
            }
        }
        #pragma unroll
        for (int r = 0; r < 4; ++r) {
            const int row = quad * 4 + r;
            float se = 0.f, sr = 0.f;
            #pragma unroll
            for (int t = 0; t < 4; ++t) {
                float v = acc[t][r];
                z[(size_t)(i0 + row) * HID + t * 16 + m] = bf16_rne(v);
                se = fmaf(v, al[t * 16 + m], se);
                sr = fmaf(v, ar[t * 16 + m], sr);
            }
            #pragma unroll
            for (int off = 1; off < 16; off <<= 1) {
                se += __shfl_xor(se, off, 64);
                sr += __shfl_xor(sr, off, 64);
            }
            if (m == 0) { el[i0 + row] = se; er[i0 + row] = sr; }
        }
    } else {
        const int r = lane & 7, g = lane >> 3;
        const int p = (b - MB_GEMM) * 32 + threadIdx.y * 8 + g;
        const int s = ps[p], d = pd[p];
        const int rb = row_start[d], re = row_start[d + 1];
        int f = 0;
        for (int e = rb + r; e < re; e += 8) f |= ((int)csr_src[e] == s) ? 1 : 0;
        #pragma unroll
        for (int off = 1; off < 8; off <<= 1) f |= __shfl_xor(f, off, 64);
        if (r == 0) found[p] = f;
    }
}

// layer-2 aggregate: writes a_s/a_d head dots only (no h).
__global__ __launch_bounds__(256) void agg2(
    const int* __restrict__ row_start, const unsigned short* __restrict__ csr_src,
    const float* __restrict__ el, const float* __restrict__ er,
    const unsigned short* __restrict__ z, const float* __restrict__ Wc,
    float* __restrict__ as, float* __restrict__ ad)
{
    const int i = blockIdx.x * 4 + threadIdx.y;
    if (i < N_NODES)
        agg_body<true>(i, threadIdx.x, row_start, csr_src, el, er, z,
                       nullptr, Wc, as, ad);
}

// final: out[p] = found ? sigmoid(a_s[s] + a_d[d] + bc) : 0
__global__ __launch_bounds__(256) void pair_tiny(
    const int* __restrict__ ps, const int* __restrict__ pd,
    const float* __restrict__ as, const float* __restrict__ ad,
    const float* __restrict__ bc, const int* __restrict__ found,
    float* __restrict__ out)
{
    const int p = blockIdx.x * 256 + threadIdx.x;
    if (p >= N_PAIRS) return;
    float v = as[ps[p]] + ad[pd[p]] + bc[0];
    float sg = 1.f / (1.f + __expf(-v));
    out[p] = found[p] ? sg : 0.f;
}

extern "C" void kernel_launch(void* const* d_in, const int* in_sizes, int n_in,
                              void* d_out, int out_size, void* d_ws, size_t ws_size,
                              hipStream_t stream)
{
    const float* feat = (const float*)d_in[0];
    const float* W1   = (const float*)d_in[1];
    const float* al1  = (const float*)d_in[2];
    const float* ar1  = (const float*)d_in[3];
    const float* W2   = (const float*)d_in[4];
    const float* al2  = (const float*)d_in[5];
    const float* ar2  = (const float*)d_in[6];
    const float* Wc   = (const float*)d_in[7];
    const float* bc   = (const float*)d_in[8];
    const int* src    = (const int*)d_in[9];
    const int* dst    = (const int*)d_in[10];
    const int* psrc   = (const int*)d_in[11];
    const int* pdst   = (const int*)d_in[12];
    float* out = (float*)d_out;

    char* ws = (char*)d_ws;
    unsigned short* z  = (unsigned short*)ws;  ws += (size_t)N_NODES * HID * 2;
    unsigned short* h1 = (unsigned short*)ws;  ws += (size_t)N_NODES * HID * 2;
    float* el = (float*)ws;               ws += (size_t)N_NODES * 4;
    float* er = (float*)ws;               ws += (size_t)N_NODES * 4;
    float* as = (float*)ws;               ws += (size_t)N_NODES * 4;
    float* ad = (float*)ws;               ws += (size_t)N_NODES * 4;
    int* row_start = (int*)ws;            ws += (size_t)(N_NODES + 1) * 4;
    int* histHi = (int*)ws;               ws += (size_t)MHIST * 4;
    int* bsumsA = (int*)ws;               ws += (size_t)(SBG + 1) * 4;
    int* found = (int*)ws;                ws += (size_t)N_PAIRS * 4;
    ws = (char*)(((uintptr_t)ws + 255) & ~(uintptr_t)255);
    unsigned* pairs = (unsigned*)ws;      ws += (size_t)N_EDGES * 4;
    unsigned short* csr_src = (unsigned short*)ws;  ws += (size_t)N_EDGES * 2;
    ws = (char*)(((uintptr_t)ws + 255) & ~(uintptr_t)255);
    unsigned short* w1hi = (unsigned short*)ws;  ws += 8192 * 2;
    unsigned short* w1lo = (unsigned short*)ws;  ws += 8192 * 2;
    unsigned short* w2hi = (unsigned short*)ws;  ws += 4096 * 2;
    unsigned short* w2lo = (unsigned short*)ws;  ws += 4096 * 2;

    dim3 b64x4(64, 4);

    // 1) histogram + W prep
    hist_prep<<<NB1 + 32, 256, 0, stream>>>(dst, histHi, W1, W2, w1hi, w1lo, w2hi, w2lo);
    // 2) scan over MHIST (tiny)
    scan1g<<<SBG, 256, 0, stream>>>(histHi, bsumsA);
    // 3) bucket scatter || layer-1 GEMM
    scatter_gemm1<<<NB1 + MB_GEMM, b64x4, 0, stream>>>(src, dst, histHi, bsumsA, pairs,
        feat, w1hi, w1lo, al1, ar1, z, el, er);
    // 4) segment sort -> row_start + csr_src (u16)
    seg_sort<<<NB1, 256, 0, stream>>>(pairs, histHi, bsumsA, row_start, csr_src);
    // 5) layer-1 aggregate
    agg1<<<NODE_BLOCKS, b64x4, 0, stream>>>(row_start, csr_src, el, er, z, h1);
    // 6) layer-2 GEMM || pair membership
    gemm2_member<<<MB_GEMM + MEMBER_BLOCKS, b64x4, 0, stream>>>(h1, w2hi, w2lo,
        al2, ar2, z, el, er, row_start, csr_src, psrc, pdst, found);
    // 7) layer-2 aggregate + head dots
    agg2<<<NODE_BLOCKS, b64x4, 0, stream>>>(row_start, csr_src, el, er, z, Wc, as, ad);
    // 8) final pair output
    pair_tiny<<<(N_PAIRS + 255) / 256, 256, 0, stream>>>(psrc, pdst, as, ad, bc, found, out);
}

// Round 16
// 194.905 us; speedup vs baseline: 1.1341x; 1.1341x over previous
//
#include <hip/hip_runtime.h>
#include <cstdint>

#define N_NODES 50000
#define N_EDGES 800000
#define N_PAIRS 200000
#define IN_DIM 128
#define HID 64
#define N_WAVES_GEMM (N_NODES / 16)           // 3125
#define NB1 196                               // high-byte bins AND edge chunks
#define CHUNK ((N_EDGES + NB1 - 1) / NB1)     // 4082
#define MHIST (NB1 * NB1)                     // 38416
#define SBG ((MHIST + 255) / 256)             // 151 scan blocks
#define MB_GEMM ((N_WAVES_GEMM + 3) / 4)      // 782
#define NODE_BLOCKS ((N_NODES + 3) / 4)       // 12500
#define MEMBER_BLOCKS (N_PAIRS / 32)          // 6250 (32 pairs/block)

typedef __attribute__((ext_vector_type(8))) short bf16x8;
typedef __attribute__((ext_vector_type(4))) float f32x4;

__device__ __forceinline__ unsigned short bf16_rne(float f) {
    unsigned u = __float_as_uint(f);
    unsigned t = u + 0x7FFFu + ((u >> 16) & 1u);
    return (unsigned short)(t >> 16);
}
__device__ __forceinline__ void bf2f(unsigned u, float& a, float& b) {
    a = __uint_as_float(u << 16);
    b = __uint_as_float(u & 0xFFFF0000u);
}

// ---- fused: MSD pass-1 histogram (blocks 0..195) + W fragment prep ----
__global__ __launch_bounds__(256) void hist_prep(
    const int* __restrict__ dst, int* __restrict__ histHi,
    const float* __restrict__ W1, const float* __restrict__ W2,
    unsigned short* __restrict__ w1hi, unsigned short* __restrict__ w1lo,
    unsigned short* __restrict__ w2hi, unsigned short* __restrict__ w2lo)
{
    const int t = threadIdx.x, b = blockIdx.x;
    if (b < NB1) {
        __shared__ int hist[256];
        hist[t] = 0; __syncthreads();
        const int beg = b * CHUNK, end = min(beg + CHUNK, N_EDGES);
        for (int e = beg + t; e < end; e += 256) atomicAdd(&hist[dst[e] >> 8], 1);
        __syncthreads();
        if (t < NB1) histHi[t * NB1 + b] = hist[t];
    } else {
        int tid = (b - NB1) * 256 + t;
        if (tid < 8192) {
            int jj = tid & 7, lane = (tid >> 3) & 63, tt = (tid >> 9) & 3, ks = tid >> 11;
            int k = ks * 32 + (lane >> 4) * 8 + jj;
            int n = tt * 16 + (lane & 15);
            float f = W1[k * HID + n];
            unsigned short hi = bf16_rne(f);
            float fhi = __uint_as_float(((unsigned)hi) << 16);
            w1hi[tid] = hi;
            w1lo[tid] = bf16_rne(f - fhi);
        }
        if (tid < 4096) {
            int jj = tid & 7, lane = (tid >> 3) & 63, tt = (tid >> 9) & 3, ks = tid >> 11;
            int k = ks * 32 + (lane >> 4) * 8 + jj;
            int n = tt * 16 + (lane & 15);
            float f = W2[k * HID + n];
            unsigned short hi = bf16_rne(f);
            float fhi = __uint_as_float(((unsigned)hi) << 16);
            w2hi[tid] = hi;
            w2lo[tid] = bf16_rne(f - fhi);
        }
    }
}

// device-wide scan step 1 (standalone, tiny)
__global__ __launch_bounds__(256) void scan1g(
    int* __restrict__ histHi, int* __restrict__ bsums)
{
    __shared__ int sh[256];
    const int t = threadIdx.x;
    const int i = blockIdx.x * 256 + t;
    int v = (i < MHIST) ? histHi[i] : 0;
    sh[t] = v; __syncthreads();
    #pragma unroll
    for (int off = 1; off < 256; off <<= 1) {
        int x = sh[t];
        int a = (t >= off) ? sh[t - off] : 0;
        __syncthreads();
        sh[t] = x + a;
        __syncthreads();
    }
    if (i < MHIST) histHi[i] = sh[t] - v;
    if (t == 255) bsums[blockIdx.x] = sh[255];
}

// in-block exclusive scan of the 151 bsums partials -> exb[]
__device__ __forceinline__ void scan_bsums(const int* __restrict__ bsums,
                                           int* sh, int* exb, int t)
{
    int v = (t < SBG) ? bsums[t] : 0;
    sh[t] = v; __syncthreads();
    #pragma unroll
    for (int off = 1; off < 256; off <<= 1) {
        int x = sh[t];
        int a = (t >= off) ? sh[t - off] : 0;
        __syncthreads();
        sh[t] = x + a;
        __syncthreads();
    }
    exb[t] = sh[t] - v;
    __syncthreads();
}

// layer-1 GEMM body: fp32 x, split-bf16 (hi*hi + hi*lo + lo*hi); z stored bf16.
__device__ __forceinline__ void gemm1_body(
    int wave, int lane,
    const float* __restrict__ x,
    const unsigned short* __restrict__ whi, const unsigned short* __restrict__ wlo,
    const float* __restrict__ al, const float* __restrict__ ar,
    unsigned short* __restrict__ z, float* __restrict__ el, float* __restrict__ er)
{
    const int i0 = wave * 16;
    const int m = lane & 15, quad = lane >> 4;
    f32x4 acc[4] = {{0.f,0.f,0.f,0.f},{0.f,0.f,0.f,0.f},{0.f,0.f,0.f,0.f},{0.f,0.f,0.f,0.f}};
    const float* xrow = x + (size_t)(i0 + m) * IN_DIM;

    #pragma unroll 1
    for (int ks = 0; ks < 4; ++ks) {
        const float4 xv0 = *(const float4*)&xrow[ks * 32 + quad * 8];
        const float4 xv1 = *(const float4*)&xrow[ks * 32 + quad * 8 + 4];
        float xs[8] = {xv0.x, xv0.y, xv0.z, xv0.w, xv1.x, xv1.y, xv1.z, xv1.w};
        bf16x8 ahi, alo;
        #pragma unroll
        for (int jj = 0; jj < 8; ++jj) {
            unsigned short hb = bf16_rne(xs[jj]);
            float fhi = __uint_as_float(((unsigned)hb) << 16);
            ahi[jj] = (short)hb;
            alo[jj] = (short)bf16_rne(xs[jj] - fhi);
        }
        #pragma unroll
        for (int t = 0; t < 4; ++t) {
            const bf16x8 bhi = *(const bf16x8*)&whi[(((ks * 4 + t) * 64) + lane) * 8];
            const bf16x8 blo = *(const bf16x8*)&wlo[(((ks * 4 + t) * 64) + lane) * 8];
            acc[t] = __builtin_amdgcn_mfma_f32_16x16x32_bf16(ahi, bhi, acc[t], 0, 0, 0);
            acc[t] = __builtin_amdgcn_mfma_f32_16x16x32_bf16(ahi, blo, acc[t], 0, 0, 0);
            acc[t] = __builtin_amdgcn_mfma_f32_16x16x32_bf16(alo, bhi, acc[t], 0, 0, 0);
        }
    }
    #pragma unroll
    for (int r = 0; r < 4; ++r) {
        const int row = quad * 4 + r;
        float se = 0.f, sr = 0.f;
        #pragma unroll
        for (int t = 0; t < 4; ++t) {
            float v = acc[t][r];
            z[(size_t)(i0 + row) * HID + t * 16 + m] = bf16_rne(v);
            se = fmaf(v, al[t * 16 + m], se);
            sr = fmaf(v, ar[t * 16 + m], sr);
        }
        #pragma unroll
        for (int off = 1; off < 16; off <<= 1) {
            se += __shfl_xor(se, off, 64);
            sr += __shfl_xor(sr, off, 64);
        }
        if (m == 0) { el[i0 + row] = se; er[i0 + row] = sr; }
    }
}

// fused: MSD pass-1 scatter (blocks 0..195) + layer-1 GEMM (blocks 196..).
__global__ __launch_bounds__(256) void scatter_gemm1(
    const int* __restrict__ src, const int* __restrict__ dst,
    const int* __restrict__ histEx, const int* __restrict__ bsums,
    unsigned* __restrict__ pairs,
    const float* __restrict__ x,
    const unsigned short* __restrict__ whi, const unsigned short* __restrict__ wlo,
    const float* __restrict__ al, const float* __restrict__ ar,
    unsigned short* __restrict__ z, float* __restrict__ el, float* __restrict__ er)
{
    const int b = blockIdx.x;
    if (b < NB1) {
        __shared__ int sh[256], exb[256], base[256];
        const int t = threadIdx.y * 64 + threadIdx.x;
        scan_bsums(bsums, sh, exb, t);
        if (t < NB1) {
            int idx = t * NB1 + b;
            base[t] = histEx[idx] + exb[idx >> 8];
        }
        __syncthreads();
        const int beg = b * CHUNK, end = min(beg + CHUNK, N_EDGES);
        for (int e = beg + t; e < end; e += 256) {
            int s = src[e], d = dst[e];
            int pos = atomicAdd(&base[d >> 8], 1);
            pairs[pos] = ((unsigned)s << 16) | (unsigned)d;   // both ids < 2^16
        }
    } else {
        const int wave = (b - NB1) * 4 + threadIdx.y;
        if (wave < N_WAVES_GEMM)
            gemm1_body(wave, threadIdx.x, x, whi, wlo, al, ar, z, el, er);
    }
}

// ---- MSD pass 2: one block per 256-node segment -> row_start + csr_src (u16) ----
__global__ __launch_bounds__(256) void seg_sort(
    const unsigned* __restrict__ pairs, const int* __restrict__ histEx,
    const int* __restrict__ bsums,
    int* __restrict__ row_start, unsigned short* __restrict__ csr_src)
{
    __shared__ int sh[256], exb[256], hist[256], sc[256], offs[256];
    const int t = threadIdx.x, b = blockIdx.x;
    scan_bsums(bsums, sh, exb, t);
    const int i0 = b * NB1;
    const int segStart = histEx[i0] + exb[i0 >> 8];
    int segEnd = N_EDGES;
    if (b < NB1 - 1) {
        const int i1 = (b + 1) * NB1;
        segEnd = histEx[i1] + exb[i1 >> 8];
    }
    hist[t] = 0; __syncthreads();
    for (int i = segStart + t; i < segEnd; i += 256)
        atomicAdd(&hist[pairs[i] & 255], 1);
    __syncthreads();
    int v = hist[t]; sc[t] = v; __syncthreads();
    #pragma unroll
    for (int off = 1; off < 256; off <<= 1) {
        int x = sc[t];
        int a = (t >= off) ? sc[t - off] : 0;
        __syncthreads();
        sc[t] = x + a;
        __syncthreads();
    }
    const int excl = sc[t] - v;
    offs[t] = segStart + excl;
    const int node = b * 256 + t;
    if (node <= N_NODES) row_start[node] = segStart + excl;
    __syncthreads();
    for (int i = segStart + t; i < segEnd; i += 256) {
        unsigned p = pairs[i];
        int pos = atomicAdd(&offs[p & 255], 1);
        csr_src[pos] = (unsigned short)(p >> 16);
    }
}

// per-dst-node softmax-aggregate + relu body. One wave per node.
// es = lane>>3 (edge slot 0..7), fl = lane&7 (8 bf16 feats = one uint4 per lane).
// 2-deep pipeline (csr 2-ahead, el/z 1-ahead). R15's 16-slot variant REGRESSED
// (agg is throughput-bound, not latency-bound; TLP already hides the chain) —
// this is the verified-best R14 structure.
// LAST=false: writes bf16 h row. LAST=true: writes head dots a_s,a_d only.
template <bool LAST>
__device__ __forceinline__ void agg_body(
    int i, int lane,
    const int* __restrict__ row_start, const unsigned short* __restrict__ csr_src,
    const float* __restrict__ el, const float* __restrict__ er,
    const unsigned short* __restrict__ z, unsigned short* __restrict__ h,
    const float* __restrict__ Wc, float* __restrict__ as, float* __restrict__ ad)
{
    const int rb = row_start[i], re = row_start[i + 1];
    const float er_i = er[i];
    const int es = lane >> 3;
    const int fl = lane & 7;

    float acc[8] = {0.f,0.f,0.f,0.f,0.f,0.f,0.f,0.f};
    float den = 0.f;

    int eA = rb + es;        bool vA = eA < re;
    int eB = eA + 8;         bool vB = eB < re;
    int sA = vA ? (int)csr_src[eA] : 0;
    int sB = vB ? (int)csr_src[eB] : 0;
    float elA = el[sA];
    uint4 zA = ((const uint4*)(z + (size_t)sA * HID))[fl];

    for (int e0 = rb; e0 < re; e0 += 8) {
        const int eC = e0 + 16 + es;
        const bool vC = eC < re;
        const int sC = vC ? (int)csr_src[eC] : 0;               // 2 ahead
        const float elB = el[sB];                                // 1 ahead
        const uint4 zB = ((const uint4*)(z + (size_t)sB * HID))[fl];

        float x = elA + er_i;
        float lr = x > 0.f ? x : 0.2f * x;
        float ex = vA ? __expf(lr) : 0.f;
        float z0, z1, z2, z3, z4, z5, z6, z7;
        bf2f(zA.x, z0, z1); bf2f(zA.y, z2, z3);
        bf2f(zA.z, z4, z5); bf2f(zA.w, z6, z7);
        acc[0] = fmaf(ex, z0, acc[0]); acc[1] = fmaf(ex, z1, acc[1]);
        acc[2] = fmaf(ex, z2, acc[2]); acc[3] = fmaf(ex, z3, acc[3]);
        acc[4] = fmaf(ex, z4, acc[4]); acc[5] = fmaf(ex, z5, acc[5]);
        acc[6] = fmaf(ex, z6, acc[6]); acc[7] = fmaf(ex, z7, acc[7]);
        den += ex;

        sA = sB; vA = vB; elA = elB; zA = zB;
        sB = sC; vB = vC;
    }
    #pragma unroll
    for (int off = 8; off < 64; off <<= 1) {
        #pragma unroll
        for (int q = 0; q < 8; ++q) acc[q] += __shfl_xor(acc[q], off, 64);
        den += __shfl_xor(den, off, 64);
    }
    if (es == 0) {
        float inv = 1.f / fmaxf(den, 1e-9f);
        float hv[8];
        #pragma unroll
        for (int q = 0; q < 8; ++q) hv[q] = fmaxf(acc[q] * inv, 0.f);
        if (LAST) {
            float ps = 0.f, pd = 0.f;
            #pragma unroll
            for (int q = 0; q < 8; ++q) {
                ps = fmaf(hv[q], Wc[fl * 8 + q], ps);
                pd = fmaf(hv[q], Wc[HID + fl * 8 + q], pd);
            }
            #pragma unroll
            for (int off = 1; off < 8; off <<= 1) {
                ps += __shfl_xor(ps, off, 64);
                pd += __shfl_xor(pd, off, 64);
            }
            if (fl == 0) { as[i] = ps; ad[i] = pd; }
        } else {
            unsigned short o[8];
            #pragma unroll
            for (int q = 0; q < 8; ++q) o[q] = bf16_rne(hv[q]);
            uint4 pk;
            pk.x = (unsigned)o[0] | ((unsigned)o[1] << 16);
            pk.y = (unsigned)o[2] | ((unsigned)o[3] << 16);
            pk.z = (unsigned)o[4] | ((unsigned)o[5] << 16);
            pk.w = (unsigned)o[6] | ((unsigned)o[7] << 16);
            ((uint4*)(h + (size_t)i * HID))[fl] = pk;
        }
    }
}

// layer-1 aggregate (standalone)
__global__ __launch_bounds__(256) void agg1(
    const int* __restrict__ row_start, const unsigned short* __restrict__ csr_src,
    const float* __restrict__ el, const float* __restrict__ er,
    const unsigned short* __restrict__ z, unsigned short* __restrict__ h)
{
    const int i = blockIdx.x * 4 + threadIdx.y;
    if (i < N_NODES)
        agg_body<false>(i, threadIdx.x, row_start, csr_src, el, er, z, h,
                        nullptr, nullptr, nullptr);
}

// fused: layer-2 GEMM (blocks 0..781) + pair membership (782..7031).
__global__ __launch_bounds__(256) void gemm2_member(
    const unsigned short* __restrict__ x,
    const unsigned short* __restrict__ whi, const unsigned short* __restrict__ wlo,
    const float* __restrict__ al, const float* __restrict__ ar,
    unsigned short* __restrict__ z, float* __restrict__ el, float* __restrict__ er,
    const int* __restrict__ row_start, const unsigned short* __restrict__ csr_src,
    const int* __restrict__ ps, const int* __restrict__ pd, int* __restrict__ found)
{
    const int lane = threadIdx.x, b = blockIdx.x;
    if (b < MB_GEMM) {
        const int wave = b * 4 + threadIdx.y;
        if (wave >= N_WAVES_GEMM) return;
        const int i0 = wave * 16;
        const int m = lane & 15, quad = lane >> 4;
        f32x4 acc[4] = {{0.f,0.f,0.f,0.f},{0.f,0.f,0.f,0.f},{0.f,0.f,0.f,0.f},{0.f,0.f,0.f,0.f}};
        const unsigned short* xrow = x + (size_t)(i0 + m) * HID;
        #pragma unroll 1
        for (int ks = 0; ks < 2; ++ks) {
            const bf16x8 a = *(const bf16x8*)&xrow[ks * 32 + quad * 8];
            #pragma unroll
            for (int t = 0; t < 4; ++t) {
                const bf16x8 bhi = *(const bf16x8*)&whi[(((ks * 4 + t) * 64) + lane) * 8];
                const bf16x8 blo = *(const bf16x8*)&wlo[(((ks * 4 + t) * 64) + lane) * 8];
                acc[t] = __builtin_amdgcn_mfma_f32_16x16x32_bf16(a, bhi, acc[t], 0, 0, 0);
                acc[t] = __builtin_amdgcn_mfma_f32_16x16x32_bf16(a, blo, acc[t], 0, 0, 0);
            }
        }
        #pragma unroll
        for (int r = 0; r < 4; ++r) {
            const int row = quad * 4 + r;
            float se = 0.f, sr = 0.f;
            #pragma unroll
            for (int t = 0; t < 4; ++t) {
                float v = acc[t][r];
                z[(size_t)(i0 + row) * HID + t * 16 + m] = bf16_rne(v);
                se = fmaf(v, al[t * 16 + m], se);
                sr = fmaf(v, ar[t * 16 + m], sr);
            }
            #pragma unroll
            for (int off = 1; off < 16; off <<= 1) {
                se += __shfl_xor(se, off, 64);
                sr += __shfl_xor(sr, off, 64);
            }
            if (m == 0) { el[i0 + row] = se; er[i0 + row] = sr; }
        }
    } else {
        const int r = lane & 7, g = lane >> 3;
        const int p = (b - MB_GEMM) * 32 + threadIdx.y * 8 + g;
        const int s = ps[p], d = pd[p];
        const int rb = row_start[d], re = row_start[d + 1];
        int f = 0;
        for (int e = rb + r; e < re; e += 8) f |= ((int)csr_src[e] == s) ? 1 : 0;
        #pragma unroll
        for (int off = 1; off < 8; off <<= 1) f |= __shfl_xor(f, off, 64);
        if (r == 0) found[p] = f;
    }
}

// layer-2 aggregate: writes a_s/a_d head dots only (no h).
__global__ __launch_bounds__(256) void agg2(
    const int* __restrict__ row_start, const unsigned short* __restrict__ csr_src,
    const float* __restrict__ el, const float* __restrict__ er,
    const unsigned short* __restrict__ z, const float* __restrict__ Wc,
    float* __restrict__ as, float* __restrict__ ad)
{
    const int i = blockIdx.x * 4 + threadIdx.y;
    if (i < N_NODES)
        agg_body<true>(i, threadIdx.x, row_start, csr_src, el, er, z,
                       nullptr, Wc, as, ad);
}

// final: out[p] = found ? sigmoid(a_s[s] + a_d[d] + bc) : 0
__global__ __launch_bounds__(256) void pair_tiny(
    const int* __restrict__ ps, const int* __restrict__ pd,
    const float* __restrict__ as, const float* __restrict__ ad,
    const float* __restrict__ bc, const int* __restrict__ found,
    float* __restrict__ out)
{
    const int p = blockIdx.x * 256 + threadIdx.x;
    if (p >= N_PAIRS) return;
    float v = as[ps[p]] + ad[pd[p]] + bc[0];
    float sg = 1.f / (1.f + __expf(-v));
    out[p] = found[p] ? sg : 0.f;
}

extern "C" void kernel_launch(void* const* d_in, const int* in_sizes, int n_in,
                              void* d_out, int out_size, void* d_ws, size_t ws_size,
                              hipStream_t stream)
{
    const float* feat = (const float*)d_in[0];
    const float* W1   = (const float*)d_in[1];
    const float* al1  = (const float*)d_in[2];
    const float* ar1  = (const float*)d_in[3];
    const float* W2   = (const float*)d_in[4];
    const float* al2  = (const float*)d_in[5];
    const float* ar2  = (const float*)d_in[6];
    const float* Wc   = (const float*)d_in[7];
    const float* bc   = (const float*)d_in[8];
    const int* src    = (const int*)d_in[9];
    const int* dst    = (const int*)d_in[10];
    const int* psrc   = (const int*)d_in[11];
    const int* pdst   = (const int*)d_in[12];
    float* out = (float*)d_out;

    char* ws = (char*)d_ws;
    unsigned short* z  = (unsigned short*)ws;  ws += (size_t)N_NODES * HID * 2;
    unsigned short* h1 = (unsigned short*)ws;  ws += (size_t)N_NODES * HID * 2;
    float* el = (float*)ws;               ws += (size_t)N_NODES * 4;
    float* er = (float*)ws;               ws += (size_t)N_NODES * 4;
    float* as = (float*)ws;               ws += (size_t)N_NODES * 4;
    float* ad = (float*)ws;               ws += (size_t)N_NODES * 4;
    int* row_start = (int*)ws;            ws += (size_t)(N_NODES + 1) * 4;
    int* histHi = (int*)ws;               ws += (size_t)MHIST * 4;
    int* bsumsA = (int*)ws;               ws += (size_t)(SBG + 1) * 4;
    int* found = (int*)ws;                ws += (size_t)N_PAIRS * 4;
    ws = (char*)(((uintptr_t)ws + 255) & ~(uintptr_t)255);
    unsigned* pairs = (unsigned*)ws;      ws += (size_t)N_EDGES * 4;
    unsigned short* csr_src = (unsigned short*)ws;  ws += (size_t)N_EDGES * 2;
    ws = (char*)(((uintptr_t)ws + 255) & ~(uintptr_t)255);
    unsigned short* w1hi = (unsigned short*)ws;  ws += 8192 * 2;
    unsigned short* w1lo = (unsigned short*)ws;  ws += 8192 * 2;
    unsigned short* w2hi = (unsigned short*)ws;  ws += 4096 * 2;
    unsigned short* w2lo = (unsigned short*)ws;  ws += 4096 * 2;

    dim3 b64x4(64, 4);

    // 1) histogram + W prep
    hist_prep<<<NB1 + 32, 256, 0, stream>>>(dst, histHi, W1, W2, w1hi, w1lo, w2hi, w2lo);
    // 2) scan over MHIST (tiny)
    scan1g<<<SBG, 256, 0, stream>>>(histHi, bsumsA);
    // 3) bucket scatter || layer-1 GEMM
    scatter_gemm1<<<NB1 + MB_GEMM, b64x4, 0, stream>>>(src, dst, histHi, bsumsA, pairs,
        feat, w1hi, w1lo, al1, ar1, z, el, er);
    // 4) segment sort -> row_start + csr_src (u16)
    seg_sort<<<NB1, 256, 0, stream>>>(pairs, histHi, bsumsA, row_start, csr_src);
    // 5) layer-1 aggregate
    agg1<<<NODE_BLOCKS, b64x4, 0, stream>>>(row_start, csr_src, el, er, z, h1);
    // 6) layer-2 GEMM || pair membership
    gemm2_member<<<MB_GEMM + MEMBER_BLOCKS, b64x4, 0, stream>>>(h1, w2hi, w2lo,
        al2, ar2, z, el, er, row_start, csr_src, psrc, pdst, found);
    // 7) layer-2 aggregate + head dots
    agg2<<<NODE_BLOCKS, b64x4, 0, stream>>>(row_start, csr_src, el, er, z, Wc, as, ad);
    // 8) final pair output
    pair_tiny<<<(N_PAIRS + 255) / 256, 256, 0, stream>>>(psrc, pdst, as, ad, bc, found, out);
}